// Round 1
// 10085.464 us; speedup vs baseline: 1.2665x; 1.2665x over previous
//
#include <hip/hip_runtime.h>
#include <math.h>

#define BB 64
#define SS 64
#define HH 512
#define VV 32000
#define TT 80

typedef __attribute__((ext_vector_type(4))) float f32x4;
typedef __attribute__((ext_vector_type(8))) short s16x8;

// Split f32 into two truncated bf16 halves: w = hi + lo + eps, |eps| <= 2^-14 |w|
__device__ __forceinline__ void split_f32(float w, short &hi, short &lo) {
    unsigned u = __float_as_uint(w);
    unsigned uh = u & 0xFFFF0000u;
    hi = (short)(uh >> 16);
    float r = w - __uint_as_float(uh);      // exact (low mantissa bits)
    lo = (short)(__float_as_uint(r) >> 16); // truncate residual
}

__global__ __launch_bounds__(256) void init_kernel(float* __restrict__ h0, int* __restrict__ tok) {
    int i = blockIdx.x * 256 + threadIdx.x;
    if (i < BB * HH) h0[i] = 0.0f;
    if (i < BB) tok[i] = 0;   // SOS_IDX = 0
}

// GRU cell: h_out = GRUCell(h_in, emb[tok[b]]) ; grid (32 j-tiles, 4 b-tiles), 256 thr
// thread = (bl = tid&15, jl = tid>>4): 16 b x 16 j per block, 6 dot-products/thread
// If h_hi/h_lo non-null, also writes the bf16x2 split of h_out (consumed by fc_mfma).
__global__ __launch_bounds__(256) void gru_step(
    const float* __restrict__ emb, const int* __restrict__ tok, int tok_stride,
    const float* __restrict__ h_in, float* __restrict__ h_out,
    const float* __restrict__ Wih, const float* __restrict__ Whh,
    const float* __restrict__ bih, const float* __restrict__ bhh,
    unsigned short* __restrict__ h_hi, unsigned short* __restrict__ h_lo)
{
    const int tid = threadIdx.x;
    const int bl = tid & 15;
    const int jl = tid >> 4;
    const int j0 = blockIdx.x * 16;
    const int b0 = blockIdx.y * 16;
    const int j = j0 + jl;
    const int b = b0 + bl;

    __shared__ float x_s[16][132];   // pad 132: 4*bl bank offset, float4-aligned
    __shared__ float h_s[16][132];

    float air = 0.f, aiz = 0.f, ain = 0.f, ahr = 0.f, ahz = 0.f, ahn = 0.f;

    const float* __restrict__ Wr = Wih + (size_t)j * HH;
    const float* __restrict__ Wz = Wih + (size_t)(j + HH) * HH;
    const float* __restrict__ Wn = Wih + (size_t)(j + 2 * HH) * HH;
    const float* __restrict__ Ur = Whh + (size_t)j * HH;
    const float* __restrict__ Uz = Whh + (size_t)(j + HH) * HH;
    const float* __restrict__ Un = Whh + (size_t)(j + 2 * HH) * HH;

    for (int k0 = 0; k0 < HH; k0 += 128) {
        #pragma unroll
        for (int i = 0; i < 2; ++i) {
            int f = tid + i * 256;        // float4 id in [0,512)
            int row = f >> 5;             // 32 float4 per 128-wide row
            int col = (f & 31) << 2;
            int tkb = tok[(size_t)(b0 + row) * tok_stride];
            *(float4*)&x_s[row][col] = *(const float4*)&emb[(size_t)tkb * HH + k0 + col];
            *(float4*)&h_s[row][col] = *(const float4*)&h_in[(size_t)(b0 + row) * HH + k0 + col];
        }
        __syncthreads();
        #pragma unroll 8
        for (int kk = 0; kk < 128; kk += 4) {
            float4 xv = *(const float4*)&x_s[bl][kk];
            float4 hv = *(const float4*)&h_s[bl][kk];
            float4 w;
            w = *(const float4*)&Wr[k0 + kk]; air += w.x*xv.x + w.y*xv.y + w.z*xv.z + w.w*xv.w;
            w = *(const float4*)&Wz[k0 + kk]; aiz += w.x*xv.x + w.y*xv.y + w.z*xv.z + w.w*xv.w;
            w = *(const float4*)&Wn[k0 + kk]; ain += w.x*xv.x + w.y*xv.y + w.z*xv.z + w.w*xv.w;
            w = *(const float4*)&Ur[k0 + kk]; ahr += w.x*hv.x + w.y*hv.y + w.z*hv.z + w.w*hv.w;
            w = *(const float4*)&Uz[k0 + kk]; ahz += w.x*hv.x + w.y*hv.y + w.z*hv.z + w.w*hv.w;
            w = *(const float4*)&Un[k0 + kk]; ahn += w.x*hv.x + w.y*hv.y + w.z*hv.z + w.w*hv.w;
        }
        __syncthreads();
    }

    float ir = air + bih[j];
    float iz = aiz + bih[j + HH];
    float in_ = ain + bih[j + 2 * HH];
    float hr = ahr + bhh[j];
    float hz = ahz + bhh[j + HH];
    float hn = ahn + bhh[j + 2 * HH];
    float r = 1.0f / (1.0f + expf(-(ir + hr)));
    float z = 1.0f / (1.0f + expf(-(iz + hz)));
    float n = tanhf(in_ + r * hn);
    float hold = h_in[(size_t)b * HH + j];
    float hnew = (1.0f - z) * n + z * hold;
    h_out[(size_t)b * HH + j] = hnew;
    if (h_hi) {
        short hi2, lo2;
        split_f32(hnew, hi2, lo2);
        h_hi[(size_t)b * HH + j] = (unsigned short)hi2;
        h_lo[(size_t)b * HH + j] = (unsigned short)lo2;
    }
}

// FC via bf16x2-split MFMA: D = Ah*Bh + Al*Bh + Ah*Bl  (f32 accumulate).
// A = h [64x512] (pre-split bf16 hi/lo), B = fcW^T (fcW f32, split in-register).
// Block: 64 vocab cols x 64 batch, 4 waves (one 16-col slab each), grid 500.
// Fragment layout (m89-verified): A lane l: h[16*mt + (l&15)][k0 + 8*(l>>4) + i]
//                                 B lane l: fcW[n0 + (l&15)][k0 + 8*(l>>4) + i]
// -> both are contiguous 16B loads from row-major storage; no LDS in main loop.
// Epilogue: bias + out-store + per-block argmax partial (val,~v packed u64) to pmax.
__global__ __launch_bounds__(256) void fc_mfma(
    const unsigned short* __restrict__ h_hi, const unsigned short* __restrict__ h_lo,
    const float* __restrict__ fcW, const float* __restrict__ fcb,
    float* __restrict__ out, unsigned long long* __restrict__ pmax, int t)
{
    const int tid  = threadIdx.x;
    const int wave = tid >> 6;
    const int lane = tid & 63;
    const int c = lane & 15;        // A-row-in-tile / B col / D col
    const int g = lane >> 4;        // k-slot group
    const int n = blockIdx.x * 64 + wave * 16 + c;   // global vocab column
    const int kbase = g * 8;

    f32x4 acc[4];
    #pragma unroll
    for (int mt = 0; mt < 4; ++mt) acc[mt] = (f32x4){0.f, 0.f, 0.f, 0.f};

    const float* __restrict__ wp = fcW + (size_t)n * HH + kbase;
    const unsigned short* __restrict__ hh = h_hi + c * HH + kbase;
    const unsigned short* __restrict__ hl = h_lo + c * HH + kbase;

    #pragma unroll 4
    for (int k0 = 0; k0 < HH; k0 += 32) {
        f32x4 w0 = *(const f32x4*)(wp + k0);
        f32x4 w1 = *(const f32x4*)(wp + k0 + 4);
        s16x8 Bh, Bl;
        #pragma unroll
        for (int e = 0; e < 4; ++e) {
            short bh, bl2;
            split_f32(w0[e], bh, bl2); Bh[e] = bh;     Bl[e] = bl2;
            split_f32(w1[e], bh, bl2); Bh[e + 4] = bh; Bl[e + 4] = bl2;
        }
        s16x8 Ah[4], Al[4];
        #pragma unroll
        for (int mt = 0; mt < 4; ++mt) {
            Ah[mt] = *(const s16x8*)(hh + (size_t)mt * 16 * HH + k0);
            Al[mt] = *(const s16x8*)(hl + (size_t)mt * 16 * HH + k0);
        }
        #pragma unroll
        for (int mt = 0; mt < 4; ++mt) {
            acc[mt] = __builtin_amdgcn_mfma_f32_16x16x32_bf16(Ah[mt], Bh, acc[mt], 0, 0, 0);
            acc[mt] = __builtin_amdgcn_mfma_f32_16x16x32_bf16(Al[mt], Bh, acc[mt], 0, 0, 0);
            acc[mt] = __builtin_amdgcn_mfma_f32_16x16x32_bf16(Ah[mt], Bl, acc[mt], 0, 0, 0);
        }
    }

    const float bias = fcb[n];
    __shared__ unsigned long long sm[4][64];
    float* __restrict__ obase = out + (size_t)t * VV + n;

    #pragma unroll
    for (int mt = 0; mt < 4; ++mt) {
        #pragma unroll
        for (int i = 0; i < 4; ++i) {
            const int b = mt * 16 + g * 4 + i;       // D row = (lane>>4)*4 + reg
            float val = acc[mt][i] + bias;
            obase[(size_t)b * (TT * VV)] = val;
            unsigned u = __float_as_uint(val);
            unsigned m = (u & 0x80000000u) ? ~u : (u | 0x80000000u);
            unsigned long long p = ((unsigned long long)m << 32) |
                                   (unsigned long long)(0xFFFFFFFFu - (unsigned)n);
            #pragma unroll
            for (int s = 1; s < 16; s <<= 1) {       // reduce over the 16 c-lanes
                unsigned long long q = __shfl_xor(p, s, 64);
                if (q > p) p = q;
            }
            if (c == 0) sm[wave][b] = p;
        }
    }
    __syncthreads();
    if (tid < 64) {
        unsigned long long best = sm[0][tid];
        #pragma unroll
        for (int w = 1; w < 4; ++w) { unsigned long long q = sm[w][tid]; if (q > best) best = q; }
        pmax[(size_t)tid * 512 + blockIdx.x] = best;
    }
}

// Final argmax over the 500 block partials per batch row (256 KB total read).
__global__ __launch_bounds__(256) void argmax_reduce(
    const unsigned long long* __restrict__ pmax, int* __restrict__ tok_next)
{
    const int b = blockIdx.x;
    const unsigned long long* __restrict__ row = pmax + (size_t)b * 512;
    const int i = threadIdx.x;
    unsigned long long best = (i < 500) ? row[i] : 0ull;
    if (i + 256 < 500) { unsigned long long q = row[i + 256]; if (q > best) best = q; }
    #pragma unroll
    for (int s = 1; s < 64; s <<= 1) {
        unsigned long long q = __shfl_xor(best, s, 64);
        if (q > best) best = q;
    }
    __shared__ unsigned long long sm[4];
    if ((i & 63) == 0) sm[i >> 6] = best;
    __syncthreads();
    if (i == 0) {
        best = sm[0];
        if (sm[1] > best) best = sm[1];
        if (sm[2] > best) best = sm[2];
        if (sm[3] > best) best = sm[3];
        tok_next[b] = (int)(0xFFFFFFFFu - (unsigned)(best & 0xFFFFFFFFull));
    }
}

extern "C" void kernel_launch(void* const* d_in, const int* in_sizes, int n_in,
                              void* d_out, int out_size, void* d_ws, size_t ws_size,
                              hipStream_t stream) {
    const int*   src   = (const int*)  d_in[0];
    const float* emb   = (const float*)d_in[1];
    const float* eWih  = (const float*)d_in[2];
    const float* eWhh  = (const float*)d_in[3];
    const float* ebih  = (const float*)d_in[4];
    const float* ebhh  = (const float*)d_in[5];
    const float* dWih  = (const float*)d_in[6];
    const float* dWhh  = (const float*)d_in[7];
    const float* dbih  = (const float*)d_in[8];
    const float* dbhh  = (const float*)d_in[9];
    const float* fcW   = (const float*)d_in[10];
    const float* fcb   = (const float*)d_in[11];
    float* out = (float*)d_out;

    // workspace layout (649 KB total)
    float* hA  = (float*)d_ws;                               // [64,512] f32
    float* hB  = hA + BB * HH;                               // [64,512] f32
    int*   tok = (int*)(hB + BB * HH);                       // [81,64]  i32
    unsigned short* hhi = (unsigned short*)(tok + (TT + 1) * BB);  // [64,512] bf16 bits
    unsigned short* hlo = hhi + BB * HH;                           // [64,512] bf16 bits
    unsigned long long* pmax = (unsigned long long*)(hlo + BB * HH); // [64,512] u64 partials

    hipLaunchKernelGGL(init_kernel, dim3(128), dim3(256), 0, stream, hA, tok);

    const float* hin = hA;
    float* hout = hB;

    // ---- encoder: token for b at time t is src[b*64 + t] (stride 64) ----
    for (int t = 0; t < SS; ++t) {
        hipLaunchKernelGGL(gru_step, dim3(32, 4), dim3(256), 0, stream,
                           emb, src + t, SS, hin, hout, eWih, eWhh, ebih, ebhh,
                           (unsigned short*)nullptr, (unsigned short*)nullptr);
        float* tmp = (float*)hin; hin = hout; hout = tmp;
    }

    // ---- decoder ----
    for (int t = 0; t < TT; ++t) {
        hipLaunchKernelGGL(gru_step, dim3(32, 4), dim3(256), 0, stream,
                           emb, tok + t * BB, 1, hin, hout, dWih, dWhh, dbih, dbhh,
                           hhi, hlo);
        float* tmp = (float*)hin; hin = hout; hout = tmp;
        hipLaunchKernelGGL(fc_mfma, dim3(500), dim3(256), 0, stream,
                           hhi, hlo, fcW, fcb, out, pmax, t);
        hipLaunchKernelGGL(argmax_reduce, dim3(64), dim3(256), 0, stream,
                           pmax, tok + (t + 1) * BB);
    }
}